// Round 29
// baseline (75.047 us; speedup 1.0000x reference)
//
#include <hip/hip_runtime.h>

typedef __attribute__((ext_vector_type(4))) float f32x4;
typedef __attribute__((ext_vector_type(2))) unsigned u32x2;
typedef __attribute__((ext_vector_type(4))) unsigned u32x4;
typedef __attribute__((ext_vector_type(8))) short bf16x8;

constexpr int Asz = 32, Isz = 256, Osz = 256;
constexpr int NI = 8;                  // 32-row iterations (256 rows/block)

// packed f32x2 -> bf16x2 (RNE); no builtin on gfx950
__device__ inline unsigned cvtpk(float lo, float hi) {
    unsigned r;
    asm("v_cvt_pk_bf16_f32 %0, %1, %2" : "=v"(r) : "v"(lo), "v"(hi));
    return r;
}

// ---------------------------------------------------------------------------
// r29: B LIVES IN AGPRs. MFMA's B operand can come from AGPRs (ISA §10);
// each wave loads its 32 B-frags (8kt x 4nf = its 64 output cols) ONCE from
// L2-resident w[a], cvt_pk's to bf16, and pins them into 128 AGPRs ("+a"
// class pin — same idiom as the proven "+v" pins, different file half that
// nothing else uses). Inner-loop MFMAs are inline asm with the B operand
// "a"-constrained: B never touches LDS or VMEM again.
// Consequences: sB deleted -> LDS 32 KB -> 2 blocks/CU (two barrier
// domains); per-iter LDS reads halve (A only). Block = (a, 256 rows, full
// O); 512 blocks (2/CU exact); 256 thr = 4 waves, wave w = cols w*64..+63.
// A path = r21's proven scheme: reg-staged bf16 fill (1-deep pinned loads,
// compiler-tracked), chunk-XOR swizzle, lgkmcnt(0)+raw s_barrier per iter,
// stores never waited, NO vmcnt anywhere (a spill would be harmless).
// ---------------------------------------------------------------------------
__global__ __launch_bounds__(256, 2) void al_gemm(const float* __restrict__ x,
                                                  const float* __restrict__ wsrc,
                                                  const float* __restrict__ bias,
                                                  float* __restrict__ out)
{
    __shared__ char sA[2][16384];   // 32 rows x 512B bf16, chunk-XOR swizzled

    // 512 blocks: xcd p&7 hosts a in {4k..4k+3}; 16 rowgroups of 256 rows.
    const int p  = blockIdx.x;
    const int q  = p >> 3;                       // 0..63
    const int a  = (p & 7) * 4 + (q & 3);
    const int b0 = (q >> 2) * 256;               // 0..15 rowgroups

    const int t    = threadIdx.x;
    const int w    = t >> 6;          // wave 0..3 = O-quarter (cols w*64..+63)
    const int lane = t & 63;
    const int llo  = lane & 15, lhi = lane >> 4;

    // ---- A fill (reg-staged, r21 scheme): thread covers rows 8w..8w+7,
    // lane holds f32 k = lane*4..+3 of each row -> 2 cvt_pk -> ds_write_b64
    // at swizzled chunk ((lane>>1)^row)*16 + (lane&1)*8.
    const float* fs[8];
    int wadr[8];
#pragma unroll
    for (int j = 0; j < 8; ++j) {
        const int lr = 8 * w + j;
        fs[j]   = x + ((size_t)(b0 + lr) * Asz + a) * Isz + lane * 4;
        wadr[j] = lr * 512 + (((lane >> 1) ^ lr) << 4) + (lane & 1) * 8;
    }
    const size_t STEP = (size_t)32 * Asz * Isz;

    f32x4 L[8];                       // 1-deep fill registers (32 VGPR)

#define FISSUE(tn) {                                                           \
    const size_t o_ = (size_t)(tn) * STEP;                                     \
    _Pragma("unroll")                                                          \
    for (int j = 0; j < 8; ++j) L[j] = *(const f32x4*)(fs[j] + o_);            \
    asm volatile("" : "+v"(L[0]), "+v"(L[1]), "+v"(L[2]), "+v"(L[3]),          \
                      "+v"(L[4]), "+v"(L[5]), "+v"(L[6]), "+v"(L[7])); }

#define FWRITE(buf) {                                                          \
    char* Ad = &sA[buf][0];                                                    \
    _Pragma("unroll")                                                          \
    for (int j = 0; j < 8; ++j)                                                \
        *(u32x2*)&Ad[wadr[j]] =                                                \
            (u32x2){cvtpk(L[j][0], L[j][1]), cvtpk(L[j][2], L[j][3])}; }

    FISSUE(0);                        // iter-0 x loads fly under the B-prologue

    // ---- B prologue: wave's 32 frags straight from global w[a] -> AGPRs.
    // frag(kt,n): o = (w*4+n)*16 + llo, i = kt*32 + lhi*8 (8 contiguous f32
    // = 2 f32x4 loads, 128B-coalesced per 16-lane group) -> 4 cvt_pk -> pin.
    u32x4 B[8][4];                    // 128 AGPRs, live for the whole kernel
    {
        const float* wa = wsrc + (size_t)a * (Osz * Isz);
#pragma unroll
        for (int kt = 0; kt < 8; ++kt)
#pragma unroll
            for (int n = 0; n < 4; ++n) {
                const int o = (w * 4 + n) * 16 + llo;
                const float* s = wa + (size_t)o * Isz + kt * 32 + lhi * 8;
                f32x4 lo = *(const f32x4*)s, hi = *(const f32x4*)(s + 4);
                u32x4 tmp;
                tmp[0] = cvtpk(lo[0], lo[1]); tmp[1] = cvtpk(lo[2], lo[3]);
                tmp[2] = cvtpk(hi[0], hi[1]); tmp[3] = cvtpk(hi[2], hi[3]);
                B[kt][n] = tmp;
                asm volatile("" : "+a"(B[kt][n]));   // pin into an AGPR quad
            }
    }

    float bv[4];
#pragma unroll
    for (int n = 0; n < 4; ++n) bv[n] = bias[a * Osz + w * 64 + n * 16 + llo];

    FWRITE(0);                        // sA[0] = F(0)
    __syncthreads();                  // one-time full drain: sA[0] visible

    for (int tn = 0; tn < NI; ++tn) {
        if (tn < NI - 1) FISSUE(tn + 1);   // fill loads fly under compute

        const char* As = &sA[tn & 1][0];
        f32x4 acc[2][4];
#pragma unroll
        for (int m = 0; m < 2; ++m)
#pragma unroll
            for (int n = 0; n < 4; ++n) acc[m][n] = (f32x4)(bv[n]);

        __builtin_amdgcn_s_setprio(1);
#pragma unroll
        for (int kt = 0; kt < 8; ++kt) {
            const int c  = kt * 4 + lhi;
            const int r1 = llo + 16;
            const bf16x8 aF0 = *(const bf16x8*)&As[llo * 512 + ((c ^ llo) << 4)];
            const bf16x8 aF1 = *(const bf16x8*)&As[r1 * 512 + ((c ^ r1) << 4)];
#pragma unroll
            for (int n = 0; n < 4; ++n) {
                asm("v_mfma_f32_16x16x32_bf16 %0, %1, %2, %0"
                    : "+v"(acc[0][n]) : "v"(aF0), "a"(B[kt][n]));
                asm("v_mfma_f32_16x16x32_bf16 %0, %1, %2, %0"
                    : "+v"(acc[1][n]) : "v"(aF1), "a"(B[kt][n]));
            }
        }
        __builtin_amdgcn_s_setprio(0);

        // stores: D[row = b0+tn*32+m*16+lhi*4+r2][col = w*64+n*16+llo]
#pragma unroll
        for (int m = 0; m < 2; ++m) {
            const int trow = b0 + tn * 32 + m * 16 + lhi * 4;
            float* op = out + ((size_t)trow * Asz + a) * Osz + w * 64 + llo;
#pragma unroll
            for (int r2 = 0; r2 < 4; ++r2)
#pragma unroll
                for (int n = 0; n < 4; ++n)
                    op[(size_t)r2 * Asz * Osz + n * 16] = acc[m][n][r2];
        }

        if (tn < NI - 1) {
            FWRITE((tn + 1) & 1);          // cvt + write next tile
            // ds_writes visible; stores/loads NOT drained (raw barrier).
            asm volatile("s_waitcnt lgkmcnt(0)" ::: "memory");
            __builtin_amdgcn_s_barrier();
        }
    }
#undef FISSUE
#undef FWRITE
}

extern "C" void kernel_launch(void* const* d_in, const int* in_sizes, int n_in,
                              void* d_out, int out_size, void* d_ws, size_t ws_size,
                              hipStream_t stream) {
    const float* x    = (const float*)d_in[0];
    const float* w    = (const float*)d_in[1];
    const float* bias = (const float*)d_in[2];
    float* out        = (float*)d_out;
    al_gemm<<<dim3(512), dim3(256), 0, stream>>>(x, w, bias, out);
}

// Round 30
// 58.481 us; speedup vs baseline: 1.2833x; 1.2833x over previous
//
#include <hip/hip_runtime.h>

typedef __attribute__((ext_vector_type(4))) float f32x4;
typedef __attribute__((ext_vector_type(2))) unsigned u32x2;
typedef __attribute__((ext_vector_type(8))) short bf16x8;

constexpr int Bsz = 4096, Asz = 32, Isz = 256, Osz = 256;
constexpr int NI = 16;                 // iterations of 32-row super-tiles

// packed f32x2 -> bf16x2 (RNE); no builtin on gfx950
__device__ inline unsigned cvtpk(float lo, float hi) {
    unsigned r;
    asm("v_cvt_pk_bf16_f32 %0, %1, %2" : "=v"(r) : "v"(lo), "v"(hi));
    return r;
}

// ---------------------------------------------------------------------------
// r30 = r25 (champion, 55.3us) + FWRITE moved to PHASE TOP: the destination
// buffer sA[(tn+1)&1] is free the moment the previous barrier retires, so the
// fill's cvt+ds_write+lgkm drain hides under the whole compute phase instead
// of sitting exposed on the pre-barrier tail (r25's per-iter critical path).
// Single register set L (write then immediately re-issue): loads still get a
// full phase of cover; 16 VGPRs freed. No new mechanisms: same pinned loads
// (compiler-tracked), lgkmcnt(0) + raw s_barrier, NO vmcnt anywhere.
// Structure: 256 blocks (1/CU), 512 threads = 8 waves, LDS 160 KB exact
// (sA 2x16KB dbuf bf16 + sB 128KB packed B), 32-row iterations.
// ---------------------------------------------------------------------------
__global__ __launch_bounds__(512, 2) void al_gemm(const float* __restrict__ x,
                                                  const float* __restrict__ wsrc,
                                                  const float* __restrict__ bias,
                                                  float* __restrict__ out)
{
    __shared__ char sA[2][16384];   // 32 rows x 512B (bf16), chunk-XOR swizzled
    __shared__ char sB[131072];     // packed B, fragment-linear

    // 256 blocks: xcd p&7 hosts a in {4k..4k+3}; rowgroup p>>5 -> 512 rows.
    const int p  = blockIdx.x;
    const int a  = (p & 7) * 4 + ((p >> 3) & 3);
    const int b0 = (p >> 5) * 512;

    const int t    = threadIdx.x;
    const int w    = t >> 6;          // wave 0..7
    const int lane = t & 63;
    const int llo  = lane & 15, lhi = lane >> 4;

    // ---- A fill (reg-staged): wave w covers super-tile-local rows 4w..4w+3.
    // Lane holds f32 k = lane*4..+3 of its row -> 2 cvt_pk -> ds_write_b64 at
    // swizzled chunk ((lane>>1)^row)*16 + (lane&1)*8.
    const float* fs[4];
    int wadr[4];
#pragma unroll
    for (int j = 0; j < 4; ++j) {
        const int lr = 4 * w + j;
        fs[j]   = x + ((size_t)(b0 + lr) * Asz + a) * Isz + lane * 4;
        wadr[j] = lr * 512 + (((lane >> 1) ^ lr) << 4) + (lane & 1) * 8;
    }
    const size_t STEP = (size_t)32 * Asz * Isz;   // 32 rows of x

    f32x4 L[4];                       // single fill set (16 VGPR)

#define FISSUE(tn) {                                                           \
    const size_t o_ = (size_t)(tn) * STEP;                                     \
    _Pragma("unroll")                                                          \
    for (int j = 0; j < 4; ++j) L[j] = *(const f32x4*)(fs[j] + o_);            \
    asm volatile("" : "+v"(L[0]), "+v"(L[1]), "+v"(L[2]), "+v"(L[3])); }

#define FWRITE(buf) {                                                          \
    char* Ad = &sA[buf][0];                                                    \
    _Pragma("unroll")                                                          \
    for (int j = 0; j < 4; ++j)                                                \
        *(u32x2*)&Ad[wadr[j]] =                                                \
            (u32x2){cvtpk(L[j][0], L[j][1]), cvtpk(L[j][2], L[j][3])}; }

    FISSUE(0);                        // F(0) in flight during the pack

    // ---- pack w[a] f32 -> sB bf16, fragment-linear — COALESCED (r19):
    // slot s = i*512+t -> 8 contiguous f32 at wa+s*8 = lane-slot of frag:
    // o = s>>5, kt = (s>>2)&7, nf = s>>9, lane_ = (o&15) | ((s&3)<<4).
    {
        const float* wa = wsrc + (size_t)a * (Osz * Isz);
#pragma unroll
        for (int i = 0; i < 16; ++i) {
            const int s     = i * 512 + t;
            const int o     = s >> 5;
            const int kt    = (s >> 2) & 7;
            const int nf    = s >> 9;
            const int lane_ = (o & 15) | ((s & 3) << 4);
            f32x4 lo = *(const f32x4*)(wa + (size_t)s * 8);
            f32x4 hi = *(const f32x4*)(wa + (size_t)s * 8 + 4);
            union { bf16x8 v; unsigned u[4]; } r;
            r.u[0] = cvtpk(lo[0], lo[1]); r.u[1] = cvtpk(lo[2], lo[3]);
            r.u[2] = cvtpk(hi[0], hi[1]); r.u[3] = cvtpk(hi[2], hi[3]);
            *(bf16x8*)&sB[(((kt * 16 + nf) * 64) + lane_) * 16] = r.v;
        }
    }

    // bias in exactly 2 VGPRs (r13 invariant)
    const float bv0 = bias[a * Osz + w * 32 + llo];
    const float bv1 = bias[a * Osz + w * 32 + 16 + llo];

    FWRITE(0);                        // sA[0] = F(0)
    FISSUE(1);                        // F(1) flies across the sync

    __syncthreads();   // one-time full drain: sA[0] + sB visible

    // compute-side A addrs: tile0 row = llo, tile1 row = llo+16;
    // chunk c = kt*4+lhi read at (c ^ row)*16.
    const int lr1 = llo + 16;

    for (int tn = 0; tn < NI; ++tn) {
        // PHASE TOP: write F(tn+1) into the buffer freed by the last barrier,
        // then immediately re-issue L with F(tn+2) (full phase of cover).
        if (tn < NI - 1) FWRITE((tn + 1) & 1);
        if (tn < NI - 2) FISSUE(tn + 2);

        const char* As = &sA[tn & 1][0];
        f32x4 acc00 = (f32x4)(bv0), acc01 = (f32x4)(bv1);   // tile0
        f32x4 acc10 = (f32x4)(bv0), acc11 = (f32x4)(bv1);   // tile1
        __builtin_amdgcn_s_setprio(1);
#pragma unroll
        for (int kt = 0; kt < 8; ++kt) {
            const int c = kt * 4 + lhi;
            const bf16x8 aF0 = *(const bf16x8*)&As[llo * 512 + ((c ^ llo) << 4)];
            const bf16x8 aF1 = *(const bf16x8*)&As[lr1 * 512 + ((c ^ lr1) << 4)];
            const bf16x8 bF0 = *(const bf16x8*)&sB[(kt * 16 + 2 * w) * 1024 + lane * 16];
            const bf16x8 bF1 = *(const bf16x8*)&sB[(kt * 16 + 2 * w + 1) * 1024 + lane * 16];
            acc00 = __builtin_amdgcn_mfma_f32_16x16x32_bf16(aF0, bF0, acc00, 0, 0, 0);
            acc01 = __builtin_amdgcn_mfma_f32_16x16x32_bf16(aF0, bF1, acc01, 0, 0, 0);
            acc10 = __builtin_amdgcn_mfma_f32_16x16x32_bf16(aF1, bF0, acc10, 0, 0, 0);
            acc11 = __builtin_amdgcn_mfma_f32_16x16x32_bf16(aF1, bF1, acc11, 0, 0, 0);
        }
        __builtin_amdgcn_s_setprio(0);

        // stores: tile0 rows b0+tn*32+lhi*4+r2, tile1 +16; NEVER waited on
        const int trow = b0 + tn * 32 + lhi * 4;
        float* op0 = out + ((size_t)trow * Asz + a) * Osz + w * 32 + llo;
        float* op1 = op0 + (size_t)16 * Asz * Osz;
#pragma unroll
        for (int r2 = 0; r2 < 4; ++r2) {
            op0[(size_t)r2 * Asz * Osz]      = acc00[r2];
            op0[(size_t)r2 * Asz * Osz + 16] = acc01[r2];
            op1[(size_t)r2 * Asz * Osz]      = acc10[r2];
            op1[(size_t)r2 * Asz * Osz + 16] = acc11[r2];
        }

        if (tn < NI - 1) {
            // ds_writes (issued at phase top, long drained) made visible;
            // stores/loads NOT drained (raw barrier).
            asm volatile("s_waitcnt lgkmcnt(0)" ::: "memory");
            __builtin_amdgcn_s_barrier();
        }
    }
#undef FISSUE
#undef FWRITE
}

extern "C" void kernel_launch(void* const* d_in, const int* in_sizes, int n_in,
                              void* d_out, int out_size, void* d_ws, size_t ws_size,
                              hipStream_t stream) {
    const float* x    = (const float*)d_in[0];
    const float* w    = (const float*)d_in[1];
    const float* bias = (const float*)d_in[2];
    float* out        = (float*)d_out;
    al_gemm<<<dim3(256), dim3(512), 0, stream>>>(x, w, bias, out);
}

// Round 31
// 57.269 us; speedup vs baseline: 1.3104x; 1.0212x over previous
//
#include <hip/hip_runtime.h>

typedef __attribute__((ext_vector_type(4))) float f32x4;
typedef __attribute__((ext_vector_type(2))) unsigned u32x2;
typedef __attribute__((ext_vector_type(8))) short bf16x8;

constexpr int Bsz = 4096, Asz = 32, Isz = 256, Osz = 256;
constexpr int NI = 16;                 // iterations of 32-row super-tiles

// packed f32x2 -> bf16x2 (RNE); no builtin on gfx950
__device__ inline unsigned cvtpk(float lo, float hi) {
    unsigned r;
    asm("v_cvt_pk_bf16_f32 %0, %1, %2" : "=v"(r) : "v"(lo), "v"(hi));
    return r;
}

// ---------------------------------------------------------------------------
// FINAL (= r25, session champion 55.3us): 256 blocks (1/CU), 512 threads =
// 8 waves, LDS 160 KB exact (sA 2x16KB dbuf bf16 + sB 128KB packed B).
// sB = w[a] packed f32->bf16 fragment-linear in the prologue (coalesced
// reads); B never touches VMEM after. 32-row iterations, 2-deep pinned
// fill pipeline (static sets LA/LB: loads for F(tn+2) issue at top of
// compute(tn) -> ~1.5K cyc latency cover), reg-staged bf16 A with chunk-XOR
// swizzle, lgkmcnt(0) + raw s_barrier per iteration, stores never waited,
// NO vmcnt / DMA / B-reg-hoist (all compiler-falsified this session).
// Structural floor: sB pins 1 block/CU -> single barrier domain -> LDS and
// HBM streams partially serialize; 55us = ~125% of the 43us HBM-only floor.
// ---------------------------------------------------------------------------
__global__ __launch_bounds__(512, 2) void al_gemm(const float* __restrict__ x,
                                                  const float* __restrict__ wsrc,
                                                  const float* __restrict__ bias,
                                                  float* __restrict__ out)
{
    __shared__ char sA[2][16384];   // 32 rows x 512B (bf16), chunk-XOR swizzled
    __shared__ char sB[131072];     // packed B, fragment-linear

    // 256 blocks: xcd p&7 hosts a in {4k..4k+3}; rowgroup p>>5 -> 512 rows.
    const int p  = blockIdx.x;
    const int a  = (p & 7) * 4 + ((p >> 3) & 3);
    const int b0 = (p >> 5) * 512;

    const int t    = threadIdx.x;
    const int w    = t >> 6;          // wave 0..7
    const int lane = t & 63;
    const int llo  = lane & 15, lhi = lane >> 4;

    // ---- A fill (reg-staged): wave w covers super-tile-local rows 4w..4w+3.
    // Lane holds f32 k = lane*4..+3 of its row -> 2 cvt_pk -> ds_write_b64 at
    // swizzled chunk ((lane>>1)^row)*16 + (lane&1)*8.
    const float* fs[4];
    int wadr[4];
#pragma unroll
    for (int j = 0; j < 4; ++j) {
        const int lr = 4 * w + j;
        fs[j]   = x + ((size_t)(b0 + lr) * Asz + a) * Isz + lane * 4;
        wadr[j] = lr * 512 + (((lane >> 1) ^ lr) << 4) + (lane & 1) * 8;
    }
    const size_t STEP = (size_t)32 * Asz * Isz;   // 32 rows of x

    f32x4 LA[4], LB[4];               // 2-deep fill pipeline (32 VGPR)

#define FISSUE(Lset, tn) {                                                     \
    const size_t o_ = (size_t)(tn) * STEP;                                     \
    _Pragma("unroll")                                                          \
    for (int j = 0; j < 4; ++j) Lset[j] = *(const f32x4*)(fs[j] + o_);         \
    asm volatile("" : "+v"(Lset[0]), "+v"(Lset[1]), "+v"(Lset[2]), "+v"(Lset[3])); }

#define FWRITE(Lset, buf) {                                                    \
    char* Ad = &sA[buf][0];                                                    \
    _Pragma("unroll")                                                          \
    for (int j = 0; j < 4; ++j)                                                \
        *(u32x2*)&Ad[wadr[j]] =                                                \
            (u32x2){cvtpk(Lset[j][0], Lset[j][1]), cvtpk(Lset[j][2], Lset[j][3])}; }

    FISSUE(LA, 0);                    // F(0) in flight during the pack

    // ---- pack w[a] f32 -> sB bf16, fragment-linear — COALESCED (r19):
    // slot s = i*512+t -> 8 contiguous f32 at wa+s*8 = lane-slot of frag:
    // o = s>>5, kt = (s>>2)&7, nf = s>>9, lane_ = (o&15) | ((s&3)<<4).
    {
        const float* wa = wsrc + (size_t)a * (Osz * Isz);
#pragma unroll
        for (int i = 0; i < 16; ++i) {
            const int s     = i * 512 + t;
            const int o     = s >> 5;
            const int kt    = (s >> 2) & 7;
            const int nf    = s >> 9;
            const int lane_ = (o & 15) | ((s & 3) << 4);
            f32x4 lo = *(const f32x4*)(wa + (size_t)s * 8);
            f32x4 hi = *(const f32x4*)(wa + (size_t)s * 8 + 4);
            union { bf16x8 v; unsigned u[4]; } r;
            r.u[0] = cvtpk(lo[0], lo[1]); r.u[1] = cvtpk(lo[2], lo[3]);
            r.u[2] = cvtpk(hi[0], hi[1]); r.u[3] = cvtpk(hi[2], hi[3]);
            *(bf16x8*)&sB[(((kt * 16 + nf) * 64) + lane_) * 16] = r.v;
        }
    }

    const float bv0 = bias[a * Osz + w * 32 + llo];
    const float bv1 = bias[a * Osz + w * 32 + 16 + llo];

    FWRITE(LA, 0);                    // sA[0] = F(0)
    FISSUE(LB, 1);                    // F(1) in flight across the sync

    __syncthreads();   // one-time full drain: sA[0] + sB visible

    // compute-side A addrs: tile0 row = llo, tile1 row = llo+16;
    // chunk c = kt*4+lhi read at (c ^ row)*16.
    const int lr1 = llo + 16;

    auto COMPUTE_STORE = [&](const char* As, int tn) {
        f32x4 acc00 = (f32x4)(bv0), acc01 = (f32x4)(bv1);   // tile0
        f32x4 acc10 = (f32x4)(bv0), acc11 = (f32x4)(bv1);   // tile1
        __builtin_amdgcn_s_setprio(1);
#pragma unroll
        for (int kt = 0; kt < 8; ++kt) {
            const int c = kt * 4 + lhi;
            const bf16x8 aF0 = *(const bf16x8*)&As[llo * 512 + ((c ^ llo) << 4)];
            const bf16x8 aF1 = *(const bf16x8*)&As[lr1 * 512 + ((c ^ lr1) << 4)];
            const bf16x8 bF0 = *(const bf16x8*)&sB[(kt * 16 + 2 * w) * 1024 + lane * 16];
            const bf16x8 bF1 = *(const bf16x8*)&sB[(kt * 16 + 2 * w + 1) * 1024 + lane * 16];
            acc00 = __builtin_amdgcn_mfma_f32_16x16x32_bf16(aF0, bF0, acc00, 0, 0, 0);
            acc01 = __builtin_amdgcn_mfma_f32_16x16x32_bf16(aF0, bF1, acc01, 0, 0, 0);
            acc10 = __builtin_amdgcn_mfma_f32_16x16x32_bf16(aF1, bF0, acc10, 0, 0, 0);
            acc11 = __builtin_amdgcn_mfma_f32_16x16x32_bf16(aF1, bF1, acc11, 0, 0, 0);
        }
        __builtin_amdgcn_s_setprio(0);

        const int trow = b0 + tn * 32 + lhi * 4;
        float* op0 = out + ((size_t)trow * Asz + a) * Osz + w * 32 + llo;
        float* op1 = op0 + (size_t)16 * Asz * Osz;
#pragma unroll
        for (int r2 = 0; r2 < 4; ++r2) {
            op0[(size_t)r2 * Asz * Osz]      = acc00[r2];
            op0[(size_t)r2 * Asz * Osz + 16] = acc01[r2];
            op1[(size_t)r2 * Asz * Osz]      = acc10[r2];
            op1[(size_t)r2 * Asz * Osz + 16] = acc11[r2];
        }
    };

#pragma unroll
    for (int i = 0; i < NI / 2; ++i) {
        // ---- tn = 2i (buffer 0): LB holds F(2i+1) ----
        if (2 * i + 2 < NI) FISSUE(LA, 2 * i + 2);   // 2 phases of cover
        COMPUTE_STORE(&sA[0][0], 2 * i);
        FWRITE(LB, 1);                                // sA[1] = F(2i+1)
        asm volatile("s_waitcnt lgkmcnt(0)" ::: "memory");
        __builtin_amdgcn_s_barrier();

        // ---- tn = 2i+1 (buffer 1): LA holds F(2i+2) ----
        if (2 * i + 3 < NI) FISSUE(LB, 2 * i + 3);
        COMPUTE_STORE(&sA[1][0], 2 * i + 1);
        if (2 * i + 2 < NI) {
            FWRITE(LA, 0);                            // sA[0] = F(2i+2)
            asm volatile("s_waitcnt lgkmcnt(0)" ::: "memory");
            __builtin_amdgcn_s_barrier();
        }
    }
#undef FISSUE
#undef FWRITE
}

extern "C" void kernel_launch(void* const* d_in, const int* in_sizes, int n_in,
                              void* d_out, int out_size, void* d_ws, size_t ws_size,
                              hipStream_t stream) {
    const float* x    = (const float*)d_in[0];
    const float* w    = (const float*)d_in[1];
    const float* bias = (const float*)d_in[2];
    float* out        = (float*)d_out;
    al_gemm<<<dim3(256), dim3(512), 0, stream>>>(x, w, bias, out);
}